// Round 10
// baseline (249.217 us; speedup 1.0000x reference)
//
#include <hip/hip_runtime.h>
#include <hip/hip_bf16.h>

#define D_MODEL 2048
#define N_HEAD 32
#define N_KV_HEAD 8
#define N_REP 4
#define D_K 64
#define S_LEN 1024
#define B_SZ 2
#define M_ROWS (B_SZ * S_LEN)      // 2048
#define KV_DIM (N_KV_HEAD * D_K)   // 512
#define QKV_N 3072                 // 2048 q | 512 k | 512 v
#define KOFF 2048
#define VOFF 2560
#define LOG2E 1.44269504088896f

typedef __attribute__((ext_vector_type(8))) short short8;   // 8 bf16 (4 VGPRs)
typedef __attribute__((ext_vector_type(4))) float f32x4;

#define EXP2F(x) __builtin_amdgcn_exp2f(x)   // v_exp_f32 (2^x native)

__device__ inline unsigned short f2bf(float f) {  // RNE fp32 -> bf16 bits
    union { float f; unsigned int u; } x{f};
    unsigned int r = x.u + 0x7fffu + ((x.u >> 16) & 1u);
    return (unsigned short)(r >> 16);
}
__device__ inline float bf2f(unsigned short b) {
    union { unsigned int u; float f; } x; x.u = ((unsigned int)b) << 16; return x.f;
}
__device__ inline void store_c(float* p, float v) { *p = v; }
__device__ inline void store_c(unsigned short* p, float v) { *p = f2bf(v); }

// async 16B global -> LDS (global_load_lds_dwordx4)
__device__ inline void load_lds16(const unsigned short* g, unsigned short* l) {
    __builtin_amdgcn_global_load_lds(
        (const __attribute__((address_space(1))) unsigned int*)g,
        (__attribute__((address_space(3))) unsigned int*)l, 16, 0, 0);
}

// ---------------- fused weight prep: all 4 W[K,N] fp32 -> Wt[N,2048] bf16 ------
// No LDS: thread t owns output row n = n0+(t>>2), k-chunk ks = k0+(t&3)*16.
// Each of the 16 reads is wave-coalesced (4 full 64B lines/instr); the two
// uint4 stores are contiguous 128B per 4 lanes (full lines).
__global__ __launch_bounds__(256) void wprep_kernel(
        const float* __restrict__ Wq_, const float* __restrict__ Wk_,
        const float* __restrict__ Wv_, const float* __restrict__ Wo_,
        unsigned short* __restrict__ WtQKV, unsigned short* __restrict__ WtO) {
    const float* src; unsigned short* dst; int N;
    switch (blockIdx.z) {
        case 0: src = Wq_; dst = WtQKV; N = D_MODEL; break;
        case 1: src = Wk_; dst = WtQKV + (size_t)KOFF * D_MODEL; N = KV_DIM; break;
        case 2: src = Wv_; dst = WtQKV + (size_t)VOFF * D_MODEL; N = KV_DIM; break;
        default: src = Wo_; dst = WtO; N = D_MODEL; break;
    }
    int n0 = blockIdx.x * 64;
    if (n0 >= N) return;
    int k0 = blockIdx.y * 64;
    int t = threadIdx.x;
    int n = n0 + (t >> 2);
    int ks = k0 + (t & 3) * 16;
    unsigned int pk[8];
#pragma unroll
    for (int i = 0; i < 8; i++) {
        float a = src[(size_t)(ks + 2 * i) * N + n];
        float b = src[(size_t)(ks + 2 * i + 1) * N + n];
        pk[i] = (unsigned int)f2bf(a) | ((unsigned int)f2bf(b) << 16);
    }
    uint4* d = (uint4*)&dst[(size_t)n * D_MODEL + ks];
    d[0] = make_uint4(pk[0], pk[1], pk[2], pk[3]);
    d[1] = make_uint4(pk[4], pk[5], pk[6], pk[7]);
}

// -------- fp32 -> bf16 cast (vectorized by 4) --------
__global__ void cast_bf_kernel(const float* __restrict__ src,
                               unsigned short* __restrict__ dst, int n4) {
    int idx = blockIdx.x * blockDim.x + threadIdx.x;
    if (idx >= n4) return;
    float4 v = ((const float4*)src)[idx];
    unsigned int lo = (unsigned int)f2bf(v.x) | ((unsigned int)f2bf(v.y) << 16);
    unsigned int hi = (unsigned int)f2bf(v.z) | ((unsigned int)f2bf(v.w) << 16);
    ((uint2*)dst)[idx] = make_uint2(lo, hi);
}

// -------- concat bias q|k|v (fp32) --------
__global__ void concat_bias_kernel(const float* __restrict__ bq, const float* __restrict__ bk,
                                   const float* __restrict__ bv, float* __restrict__ dst) {
    int i = blockIdx.x * blockDim.x + threadIdx.x;
    if (i >= QKV_N) return;
    dst[i] = (i < KOFF) ? bq[i] : (i < VOFF) ? bk[i - KOFF] : bv[i - VOFF];
}

// ---------------- bf16 GEMM: C[M,N] = A[M,K] * Bt[N,K]^T + bias ------
// BM=128, BN=64, BK=64, 256 thr = 4 waves (2x2); wave = 64x32 (4x2 16x16x32 frags).
// global_load_lds w=16 staging, XOR chunk swizzle absorbed into global address.
template <typename TC>
__global__ __launch_bounds__(256) void gemm_bf16_kernel(
        const unsigned short* __restrict__ A,   // [M][K] bf16
        const unsigned short* __restrict__ Bt,  // [N][K] bf16
        const float* __restrict__ bias,
        TC* __restrict__ C, int M, int N, int K) {
    __shared__ unsigned short As[128 * 64];
    __shared__ unsigned short Bs[64 * 64];
    const int tid = threadIdx.x, lane = tid & 63;
    const int w = tid >> 6, wm = w >> 1, wn = w & 1;
    const int quad = lane >> 4, lr = lane & 15;
    const int bm = blockIdx.y * 128, bn = blockIdx.x * 64;

    f32x4 acc[4][2];
#pragma unroll
    for (int i = 0; i < 4; i++)
#pragma unroll
        for (int j = 0; j < 2; j++) acc[i][j] = (f32x4){0.f, 0.f, 0.f, 0.f};

    for (int k0 = 0; k0 < K; k0 += 64) {
        __syncthreads();
        // A: 128 rows x 8 chunks = 1024 slots; B: 64 rows x 8 = 512 slots
#pragma unroll
        for (int it = 0; it < 4; it++) {
            int slot = it * 256 + tid;
            int row = slot >> 3;
            int qc = (slot & 7) ^ (row & 7);
            load_lds16(A + (size_t)(bm + row) * K + k0 + qc * 8, &As[slot * 8]);
        }
#pragma unroll
        for (int it = 0; it < 2; it++) {
            int slot = it * 256 + tid;
            int row = slot >> 3;
            int qc = (slot & 7) ^ (row & 7);
            load_lds16(Bt + (size_t)(bn + row) * K + k0 + qc * 8, &Bs[slot * 8]);
        }
        __syncthreads();
#pragma unroll
        for (int ks = 0; ks < 2; ks++) {
            short8 af[4], bf[2];
#pragma unroll
            for (int i = 0; i < 4; i++) {
                int row = wm * 64 + i * 16 + lr;
                af[i] = *(const short8*)&As[(row * 8 + ((ks * 4 + quad) ^ (lr & 7))) * 8];
            }
#pragma unroll
            for (int j = 0; j < 2; j++) {
                int row = wn * 32 + j * 16 + lr;
                bf[j] = *(const short8*)&Bs[(row * 8 + ((ks * 4 + quad) ^ (lr & 7))) * 8];
            }
#pragma unroll
            for (int i = 0; i < 4; i++)
#pragma unroll
                for (int j = 0; j < 2; j++)
                    acc[i][j] = __builtin_amdgcn_mfma_f32_16x16x32_bf16(af[i], bf[j], acc[i][j], 0, 0, 0);
        }
    }
#pragma unroll
    for (int i = 0; i < 4; i++) {
#pragma unroll
        for (int j = 0; j < 2; j++) {
            int col = bn + wn * 32 + j * 16 + lr;
            int row0 = bm + wm * 64 + i * 16 + quad * 4;
            float bj = bias[col];
#pragma unroll
            for (int r = 0; r < 4; r++)
                store_c(&C[(size_t)(row0 + r) * N + col], acc[i][j][r] + bj);
        }
    }
}

// -------- fused RoPE in-place on bf16 QKV buffer (q scaled by 0.125*log2e) -----
// inv_freq via exp2; fast __sinf/__cosf (ang <= 1024 rad -> err ~4e-4 << bf16 eps)
__global__ void rope_bf_kernel(unsigned short* __restrict__ t) {
    const int QI = M_ROWS * N_HEAD * 32;          // q items
    const int TOT = QI + M_ROWS * N_KV_HEAD * 32; // + k items
    int idx = blockIdx.x * blockDim.x + threadIdx.x;
    if (idx >= TOT) return;
    int col_off, n_heads;
    float scale;
    if (idx < QI) { col_off = 0; n_heads = N_HEAD; scale = 0.125f * LOG2E; }
    else { idx -= QI; col_off = KOFF; n_heads = N_KV_HEAD; scale = 1.0f; }
    int i = idx & 31;
    int hh = (idx >> 5) % n_heads;
    int r = idx / (32 * n_heads);
    int s = r % S_LEN;
    float inv_freq = EXP2F((float)i * -0.41524101186f);  // 2^(-i*2/64*log2(1e4))
    float ang = (float)s * inv_freq;
    float c = __cosf(ang), sn = __sinf(ang);
    unsigned short* p = t + (size_t)r * QKV_N + col_off + hh * D_K + 2 * i;
    float te = bf2f(p[0]), to = bf2f(p[1]);
    p[0] = f2bf((te * c - to * sn) * scale);
    p[1] = f2bf((te * sn + to * c) * scale);
}

// ---------------- MFMA flash attention ----------------
// Block = 256 thr = 4 waves, one (b,h), ONE 64-row q-tile (qt = 15-bx so the
// long blocks dispatch first). Grid 16x32x2 = 1024 blocks for occupancy.
// Scores in log2 domain (q pre-scaled 0.125*log2e) -> exp2 softmax.
#define AST 72
__device__ __forceinline__ void attn_tile(
        int w, int quad, int lr, bool diag,
        const unsigned short* Ks, const unsigned short* Vt, unsigned short* Ps,
        const short8* aq, f32x4* oacc, float* mrow, float* lrow) {
    f32x4 s[4];
#pragma unroll
    for (int cf = 0; cf < 4; cf++) s[cf] = (f32x4){0.f, 0.f, 0.f, 0.f};
#pragma unroll
    for (int ks = 0; ks < 2; ks++) {
#pragma unroll
        for (int cf = 0; cf < 4; cf++) {
            short8 bk = *(const short8*)&Ks[(cf * 16 + lr) * AST + ks * 32 + quad * 8];
            s[cf] = __builtin_amdgcn_mfma_f32_16x16x32_bf16(aq[ks], bk, s[cf], 0, 0, 0);
        }
    }
    if (diag) {
#pragma unroll
        for (int cf = 0; cf < 4; cf++) {
            int key = cf * 16 + lr;
#pragma unroll
            for (int r = 0; r < 4; r++)
                if (key > w * 16 + quad * 4 + r) s[cf][r] = -1e30f;
        }
    }
    float corr[4];
#pragma unroll
    for (int r = 0; r < 4; r++) {
        float rm = fmaxf(fmaxf(s[0][r], s[1][r]), fmaxf(s[2][r], s[3][r]));
        rm = fmaxf(rm, __shfl_xor(rm, 1));
        rm = fmaxf(rm, __shfl_xor(rm, 2));
        rm = fmaxf(rm, __shfl_xor(rm, 4));
        rm = fmaxf(rm, __shfl_xor(rm, 8));
        float mn = fmaxf(mrow[r], rm);
        corr[r] = EXP2F(mrow[r] - mn);
        mrow[r] = mn;
        float rs = 0.f;
#pragma unroll
        for (int cf = 0; cf < 4; cf++) {
            float p = EXP2F(s[cf][r] - mn);
            union { float f; unsigned int u; } px{p};
            px.u &= 0xFFFF0000u;               // truncate to bf16 (consistent l)
            Ps[(w * 16 + quad * 4 + r) * AST + cf * 16 + lr] =
                (unsigned short)(px.u >> 16);
            rs += px.f;
        }
        rs += __shfl_xor(rs, 1);
        rs += __shfl_xor(rs, 2);
        rs += __shfl_xor(rs, 4);
        rs += __shfl_xor(rs, 8);
        lrow[r] = lrow[r] * corr[r] + rs;
    }
#pragma unroll
    for (int cf = 0; cf < 4; cf++)
#pragma unroll
        for (int r = 0; r < 4; r++) oacc[cf][r] *= corr[r];
#pragma unroll
    for (int ks = 0; ks < 2; ks++) {
        short8 ap = *(const short8*)&Ps[(w * 16 + lr) * AST + ks * 32 + quad * 8];
#pragma unroll
        for (int cf = 0; cf < 4; cf++) {
            short8 bv = *(const short8*)&Vt[(cf * 16 + lr) * AST + ks * 32 + quad * 8];
            oacc[cf] = __builtin_amdgcn_mfma_f32_16x16x32_bf16(ap, bv, oacc[cf], 0, 0, 0);
        }
    }
}

__global__ __launch_bounds__(256) void attn_mfma_kernel(
        const unsigned short* __restrict__ qkv,   // [M_ROWS][QKV_N] bf16
        unsigned short* __restrict__ obf) {       // [M_ROWS][D_MODEL] bf16
    __shared__ unsigned short Ks[64 * AST];
    __shared__ unsigned short Vt[64 * AST];
    __shared__ unsigned short Ps[64 * AST];
    const int tid = threadIdx.x;
    const int w = tid >> 6, lane = tid & 63;
    const int lr = lane & 15, quad = lane >> 4;
    const int h = blockIdx.y, b = blockIdx.z;
    const int kvh = h >> 2;
    const unsigned short* kb = qkv + (size_t)(b * S_LEN) * QKV_N + KOFF + kvh * D_K;
    const unsigned short* vb = qkv + (size_t)(b * S_LEN) * QKV_N + VOFF + kvh * D_K;

    const int qt = 15 - (int)blockIdx.x;   // long blocks first (LPT)
    const int q0 = qt * 64;

    short8 aq[2];
    {
        const unsigned short* qp = qkv + (size_t)(b * S_LEN + q0 + w * 16 + lr) * QKV_N
                                   + h * D_K + quad * 8;
        aq[0] = *(const short8*)qp;
        aq[1] = *(const short8*)(qp + 32);
    }
    f32x4 oacc[4];
#pragma unroll
    for (int cf = 0; cf < 4; cf++) oacc[cf] = (f32x4){0.f, 0.f, 0.f, 0.f};
    float mrow[4] = {-1e30f, -1e30f, -1e30f, -1e30f};
    float lrow[4] = {0.f, 0.f, 0.f, 0.f};

    for (int t = 0; t <= qt; t++) {
        const int j0 = t * 64;
        __syncthreads();
        // stage K tile [64 keys][64 dims]
#pragma unroll
        for (int it = 0; it < 2; it++) {
            int f = it * 256 + tid;
            int key = f >> 3, d8 = (f & 7) * 8;
            *(uint4*)&Ks[key * AST + d8] =
                *(const uint4*)(kb + (size_t)(j0 + key) * QKV_N + d8);
        }
        // stage V transposed: Vt[dim][key], u32 pair-packed writes
        {
            int kp = tid & 31, dg = tid >> 5;    // key pair, dim group (8 dims)
            unsigned short ta[8], tb[8];
            *(uint4*)ta = *(const uint4*)(vb + (size_t)(j0 + 2 * kp) * QKV_N + dg * 8);
            *(uint4*)tb = *(const uint4*)(vb + (size_t)(j0 + 2 * kp + 1) * QKV_N + dg * 8);
#pragma unroll
            for (int i = 0; i < 8; i++) {
                unsigned int pk = (unsigned int)ta[i] | ((unsigned int)tb[i] << 16);
                *(unsigned int*)&Vt[(dg * 8 + i) * AST + 2 * kp] = pk;
            }
        }
        __syncthreads();
        attn_tile(w, quad, lr, t == qt, Ks, Vt, Ps, aq, oacc, mrow, lrow);
    }
#pragma unroll
    for (int r = 0; r < 4; r++) {
        float inv = 1.f / lrow[r];
        int row = b * S_LEN + q0 + w * 16 + quad * 4 + r;
#pragma unroll
        for (int cf = 0; cf < 4; cf++)
            obf[(size_t)row * D_MODEL + h * D_K + cf * 16 + lr] = f2bf(oacc[cf][r] * inv);
    }
}

extern "C" void kernel_launch(void* const* d_in, const int* in_sizes, int n_in,
                              void* d_out, int out_size, void* d_ws, size_t ws_size,
                              hipStream_t stream) {
    const float* x  = (const float*)d_in[0];
    const float* Wq = (const float*)d_in[1];
    const float* bq = (const float*)d_in[2];
    const float* Wk = (const float*)d_in[3];
    const float* bk = (const float*)d_in[4];
    const float* Wv = (const float*)d_in[5];
    const float* bv = (const float*)d_in[6];
    const float* Wo = (const float*)d_in[7];
    const float* bo = (const float*)d_in[8];
    float* out = (float*)d_out;

    // ws (bf16 elems): xbf/obf 8MB | WtQKV 12MB | WtO 8MB | qkv 12MB | bias 12KB = 40MB
    unsigned short* xbf   = (unsigned short*)d_ws;                       // [2048][2048]
    unsigned short* WtQKV = xbf + (size_t)M_ROWS * D_MODEL;              // [3072][2048]
    unsigned short* WtO   = WtQKV + (size_t)QKV_N * D_MODEL;             // [2048][2048]
    unsigned short* qkv   = WtO + (size_t)D_MODEL * D_MODEL;             // [2048][3072]
    float* bias_qkv       = (float*)(qkv + (size_t)M_ROWS * QKV_N);      // [3072]
    unsigned short* obf   = xbf;  // xbf consumed by QKV GEMM before attn writes

    dim3 gb(256);

    cast_bf_kernel<<<(M_ROWS * D_MODEL / 4 + 255) / 256, gb, 0, stream>>>(x, xbf, M_ROWS * D_MODEL / 4);
    wprep_kernel<<<dim3(32, 32, 4), gb, 0, stream>>>(Wq, Wk, Wv, Wo, WtQKV, WtO);
    concat_bias_kernel<<<(QKV_N + 255) / 256, gb, 0, stream>>>(bq, bk, bv, bias_qkv);
    // fused QKV projection (bf16 out): 48 x 16 = 768 blocks
    gemm_bf16_kernel<unsigned short><<<dim3(QKV_N / 64, M_ROWS / 128), gb, 0, stream>>>(
        xbf, WtQKV, bias_qkv, qkv, M_ROWS, QKV_N, D_MODEL);
    // fused RoPE (q scaled by 0.125*log2e for exp2 softmax)
    rope_bf_kernel<<<(M_ROWS * (N_HEAD + N_KV_HEAD) * 32 + 255) / 256, gb, 0, stream>>>(qkv);
    // attention: one q-tile per block, 1024 blocks
    attn_mfma_kernel<<<dim3(16, N_HEAD, B_SZ), gb, 0, stream>>>(qkv, obf);
    // O projection (fp32 out): 32 x 16 = 512 blocks
    gemm_bf16_kernel<float><<<dim3(D_MODEL / 64, M_ROWS / 128), gb, 0, stream>>>(
        obf, WtO, bo, out, M_ROWS, D_MODEL, D_MODEL);
}

// Round 11
// 232.810 us; speedup vs baseline: 1.0705x; 1.0705x over previous
//
#include <hip/hip_runtime.h>
#include <hip/hip_bf16.h>

#define D_MODEL 2048
#define N_HEAD 32
#define N_KV_HEAD 8
#define N_REP 4
#define D_K 64
#define S_LEN 1024
#define B_SZ 2
#define M_ROWS (B_SZ * S_LEN)      // 2048
#define KV_DIM (N_KV_HEAD * D_K)   // 512
#define QKV_N 3072                 // 2048 q | 512 k | 512 v
#define KOFF 2048
#define VOFF 2560
#define LOG2E 1.44269504088896f

typedef __attribute__((ext_vector_type(8))) short short8;   // 8 bf16 (4 VGPRs)
typedef __attribute__((ext_vector_type(4))) float f32x4;

#define EXP2F(x) __builtin_amdgcn_exp2f(x)   // v_exp_f32 (2^x native)

__device__ inline unsigned short f2bf(float f) {  // RNE fp32 -> bf16 bits
    union { float f; unsigned int u; } x{f};
    unsigned int r = x.u + 0x7fffu + ((x.u >> 16) & 1u);
    return (unsigned short)(r >> 16);
}
__device__ inline float bf2f(unsigned short b) {
    union { unsigned int u; float f; } x; x.u = ((unsigned int)b) << 16; return x.f;
}
__device__ inline void store_c(float* p, float v) { *p = v; }
__device__ inline void store_c(unsigned short* p, float v) { *p = f2bf(v); }

// async 16B global -> LDS (global_load_lds_dwordx4)
__device__ inline void load_lds16(const unsigned short* g, unsigned short* l) {
    __builtin_amdgcn_global_load_lds(
        (const __attribute__((address_space(1))) unsigned int*)g,
        (__attribute__((address_space(3))) unsigned int*)l, 16, 0, 0);
}

// ---------------- fused weight prep: all 4 W[K,N] fp32 -> Wt[N,2048] bf16 ------
__global__ __launch_bounds__(256) void wprep_kernel(
        const float* __restrict__ Wq_, const float* __restrict__ Wk_,
        const float* __restrict__ Wv_, const float* __restrict__ Wo_,
        unsigned short* __restrict__ WtQKV, unsigned short* __restrict__ WtO) {
    const float* src; unsigned short* dst; int N;
    switch (blockIdx.z) {
        case 0: src = Wq_; dst = WtQKV; N = D_MODEL; break;
        case 1: src = Wk_; dst = WtQKV + (size_t)KOFF * D_MODEL; N = KV_DIM; break;
        case 2: src = Wv_; dst = WtQKV + (size_t)VOFF * D_MODEL; N = KV_DIM; break;
        default: src = Wo_; dst = WtO; N = D_MODEL; break;
    }
    int n0 = blockIdx.x * 64;
    if (n0 >= N) return;
    int k0 = blockIdx.y * 64;
    int t = threadIdx.x;
    int n = n0 + (t >> 2);
    int ks = k0 + (t & 3) * 16;
    unsigned int pk[8];
#pragma unroll
    for (int i = 0; i < 8; i++) {
        float a = src[(size_t)(ks + 2 * i) * N + n];
        float b = src[(size_t)(ks + 2 * i + 1) * N + n];
        pk[i] = (unsigned int)f2bf(a) | ((unsigned int)f2bf(b) << 16);
    }
    uint4* d = (uint4*)&dst[(size_t)n * D_MODEL + ks];
    d[0] = make_uint4(pk[0], pk[1], pk[2], pk[3]);
    d[1] = make_uint4(pk[4], pk[5], pk[6], pk[7]);
}

// -------- fp32 -> bf16 cast (vectorized by 4) --------
__global__ void cast_bf_kernel(const float* __restrict__ src,
                               unsigned short* __restrict__ dst, int n4) {
    int idx = blockIdx.x * blockDim.x + threadIdx.x;
    if (idx >= n4) return;
    float4 v = ((const float4*)src)[idx];
    unsigned int lo = (unsigned int)f2bf(v.x) | ((unsigned int)f2bf(v.y) << 16);
    unsigned int hi = (unsigned int)f2bf(v.z) | ((unsigned int)f2bf(v.w) << 16);
    ((uint2*)dst)[idx] = make_uint2(lo, hi);
}

// -------- concat bias q|k|v (fp32) --------
__global__ void concat_bias_kernel(const float* __restrict__ bq, const float* __restrict__ bk,
                                   const float* __restrict__ bv, float* __restrict__ dst) {
    int i = blockIdx.x * blockDim.x + threadIdx.x;
    if (i >= QKV_N) return;
    dst[i] = (i < KOFF) ? bq[i] : (i < VOFF) ? bk[i - KOFF] : bv[i - VOFF];
}

// ---------------- bf16 GEMM: C[M,N] = A[M,K] * Bt[N,K]^T + bias ------
// BM=128, BN=64, BK=64, 256 thr = 4 waves (2x2); wave = 64x32 (4x2 16x16x32 frags).
template <typename TC>
__global__ __launch_bounds__(256) void gemm_bf16_kernel(
        const unsigned short* __restrict__ A,   // [M][K] bf16
        const unsigned short* __restrict__ Bt,  // [N][K] bf16
        const float* __restrict__ bias,
        TC* __restrict__ C, int M, int N, int K) {
    __shared__ unsigned short As[128 * 64];
    __shared__ unsigned short Bs[64 * 64];
    const int tid = threadIdx.x, lane = tid & 63;
    const int w = tid >> 6, wm = w >> 1, wn = w & 1;
    const int quad = lane >> 4, lr = lane & 15;
    const int bm = blockIdx.y * 128, bn = blockIdx.x * 64;

    f32x4 acc[4][2];
#pragma unroll
    for (int i = 0; i < 4; i++)
#pragma unroll
        for (int j = 0; j < 2; j++) acc[i][j] = (f32x4){0.f, 0.f, 0.f, 0.f};

    for (int k0 = 0; k0 < K; k0 += 64) {
        __syncthreads();
#pragma unroll
        for (int it = 0; it < 4; it++) {
            int slot = it * 256 + tid;
            int row = slot >> 3;
            int qc = (slot & 7) ^ (row & 7);
            load_lds16(A + (size_t)(bm + row) * K + k0 + qc * 8, &As[slot * 8]);
        }
#pragma unroll
        for (int it = 0; it < 2; it++) {
            int slot = it * 256 + tid;
            int row = slot >> 3;
            int qc = (slot & 7) ^ (row & 7);
            load_lds16(Bt + (size_t)(bn + row) * K + k0 + qc * 8, &Bs[slot * 8]);
        }
        __syncthreads();
#pragma unroll
        for (int ks = 0; ks < 2; ks++) {
            short8 af[4], bf[2];
#pragma unroll
            for (int i = 0; i < 4; i++) {
                int row = wm * 64 + i * 16 + lr;
                af[i] = *(const short8*)&As[(row * 8 + ((ks * 4 + quad) ^ (lr & 7))) * 8];
            }
#pragma unroll
            for (int j = 0; j < 2; j++) {
                int row = wn * 32 + j * 16 + lr;
                bf[j] = *(const short8*)&Bs[(row * 8 + ((ks * 4 + quad) ^ (lr & 7))) * 8];
            }
#pragma unroll
            for (int i = 0; i < 4; i++)
#pragma unroll
                for (int j = 0; j < 2; j++)
                    acc[i][j] = __builtin_amdgcn_mfma_f32_16x16x32_bf16(af[i], bf[j], acc[i][j], 0, 0, 0);
        }
    }
#pragma unroll
    for (int i = 0; i < 4; i++) {
#pragma unroll
        for (int j = 0; j < 2; j++) {
            int col = bn + wn * 32 + j * 16 + lr;
            int row0 = bm + wm * 64 + i * 16 + quad * 4;
            float bj = bias[col];
#pragma unroll
            for (int r = 0; r < 4; r++)
                store_c(&C[(size_t)(row0 + r) * N + col], acc[i][j][r] + bj);
        }
    }
}

// -------- fused RoPE in-place on bf16 QKV buffer (q scaled by 0.125*log2e) -----
__global__ void rope_bf_kernel(unsigned short* __restrict__ t) {
    const int QI = M_ROWS * N_HEAD * 32;          // q items
    const int TOT = QI + M_ROWS * N_KV_HEAD * 32; // + k items
    int idx = blockIdx.x * blockDim.x + threadIdx.x;
    if (idx >= TOT) return;
    int col_off, n_heads;
    float scale;
    if (idx < QI) { col_off = 0; n_heads = N_HEAD; scale = 0.125f * LOG2E; }
    else { idx -= QI; col_off = KOFF; n_heads = N_KV_HEAD; scale = 1.0f; }
    int i = idx & 31;
    int hh = (idx >> 5) % n_heads;
    int r = idx / (32 * n_heads);
    int s = r % S_LEN;
    float inv_freq = EXP2F((float)i * -0.41524101186f);  // 2^(-i*2/64*log2(1e4))
    float ang = (float)s * inv_freq;
    float c = __cosf(ang), sn = __sinf(ang);
    unsigned short* p = t + (size_t)r * QKV_N + col_off + hh * D_K + 2 * i;
    float te = bf2f(p[0]), to = bf2f(p[1]);
    p[0] = f2bf((te * c - to * sn) * scale);
    p[1] = f2bf((te * sn + to * c) * scale);
}

// ---------------- MFMA flash attention (paired + register prefetch) ----------
// Block = 256 thr = 4 waves, one (b,h); q-tiles qtA=bx (0..7) and qtB=15-bx share
// each staged K/V tile (phases = qtB+1). Next tile's K/V global loads are issued
// into registers right after the staging barrier, draining during compute.
#define AST 72
struct Pre { uint4 k0, k1, v0, v1; };

__device__ __forceinline__ void issue_pre(const unsigned short* kb,
                                          const unsigned short* vb,
                                          int j0, int tid, Pre& p) {
    int f0 = tid, f1 = tid + 256;
    p.k0 = *(const uint4*)(kb + (size_t)(j0 + (f0 >> 3)) * QKV_N + (f0 & 7) * 8);
    p.k1 = *(const uint4*)(kb + (size_t)(j0 + (f1 >> 3)) * QKV_N + (f1 & 7) * 8);
    int kp = tid & 31, dg = tid >> 5;
    p.v0 = *(const uint4*)(vb + (size_t)(j0 + 2 * kp) * QKV_N + dg * 8);
    p.v1 = *(const uint4*)(vb + (size_t)(j0 + 2 * kp + 1) * QKV_N + dg * 8);
}
__device__ __forceinline__ void commit_pre(unsigned short* Ks, unsigned short* Vt,
                                           int tid, const Pre& p) {
    int f0 = tid, f1 = tid + 256;
    *(uint4*)&Ks[(f0 >> 3) * AST + (f0 & 7) * 8] = p.k0;
    *(uint4*)&Ks[(f1 >> 3) * AST + (f1 & 7) * 8] = p.k1;
    int kp = tid & 31, dg = tid >> 5;
    const unsigned short* ta = (const unsigned short*)&p.v0;
    const unsigned short* tb = (const unsigned short*)&p.v1;
#pragma unroll
    for (int i = 0; i < 8; i++) {
        unsigned int pk = (unsigned int)ta[i] | ((unsigned int)tb[i] << 16);
        *(unsigned int*)&Vt[(dg * 8 + i) * AST + 2 * kp] = pk;
    }
}

__device__ __forceinline__ void attn_tile(
        int w, int quad, int lr, bool diag,
        const unsigned short* Ks, const unsigned short* Vt, unsigned short* Ps,
        const short8* aq, f32x4* oacc, float* mrow, float* lrow) {
    f32x4 s[4];
#pragma unroll
    for (int cf = 0; cf < 4; cf++) s[cf] = (f32x4){0.f, 0.f, 0.f, 0.f};
#pragma unroll
    for (int ks = 0; ks < 2; ks++) {
#pragma unroll
        for (int cf = 0; cf < 4; cf++) {
            short8 bk = *(const short8*)&Ks[(cf * 16 + lr) * AST + ks * 32 + quad * 8];
            s[cf] = __builtin_amdgcn_mfma_f32_16x16x32_bf16(aq[ks], bk, s[cf], 0, 0, 0);
        }
    }
    if (diag) {
#pragma unroll
        for (int cf = 0; cf < 4; cf++) {
            int key = cf * 16 + lr;
#pragma unroll
            for (int r = 0; r < 4; r++)
                if (key > w * 16 + quad * 4 + r) s[cf][r] = -1e30f;
        }
    }
    float corr[4];
#pragma unroll
    for (int r = 0; r < 4; r++) {
        float rm = fmaxf(fmaxf(s[0][r], s[1][r]), fmaxf(s[2][r], s[3][r]));
        rm = fmaxf(rm, __shfl_xor(rm, 1));
        rm = fmaxf(rm, __shfl_xor(rm, 2));
        rm = fmaxf(rm, __shfl_xor(rm, 4));
        rm = fmaxf(rm, __shfl_xor(rm, 8));
        float mn = fmaxf(mrow[r], rm);
        corr[r] = EXP2F(mrow[r] - mn);
        mrow[r] = mn;
        float rs = 0.f;
#pragma unroll
        for (int cf = 0; cf < 4; cf++) {
            float p = EXP2F(s[cf][r] - mn);
            union { float f; unsigned int u; } px{p};
            px.u &= 0xFFFF0000u;               // truncate to bf16 (consistent l)
            Ps[(w * 16 + quad * 4 + r) * AST + cf * 16 + lr] =
                (unsigned short)(px.u >> 16);
            rs += px.f;
        }
        rs += __shfl_xor(rs, 1);
        rs += __shfl_xor(rs, 2);
        rs += __shfl_xor(rs, 4);
        rs += __shfl_xor(rs, 8);
        lrow[r] = lrow[r] * corr[r] + rs;
    }
#pragma unroll
    for (int cf = 0; cf < 4; cf++)
#pragma unroll
        for (int r = 0; r < 4; r++) oacc[cf][r] *= corr[r];
#pragma unroll
    for (int ks = 0; ks < 2; ks++) {
        short8 ap = *(const short8*)&Ps[(w * 16 + lr) * AST + ks * 32 + quad * 8];
#pragma unroll
        for (int cf = 0; cf < 4; cf++) {
            short8 bv = *(const short8*)&Vt[(cf * 16 + lr) * AST + ks * 32 + quad * 8];
            oacc[cf] = __builtin_amdgcn_mfma_f32_16x16x32_bf16(ap, bv, oacc[cf], 0, 0, 0);
        }
    }
}

__global__ __launch_bounds__(256) void attn_mfma_kernel(
        const unsigned short* __restrict__ qkv,   // [M_ROWS][QKV_N] bf16
        unsigned short* __restrict__ obf) {       // [M_ROWS][D_MODEL] bf16
    __shared__ unsigned short Ks[64 * AST];
    __shared__ unsigned short Vt[64 * AST];
    __shared__ unsigned short Ps[64 * AST];
    const int tid = threadIdx.x;
    const int w = tid >> 6, lane = tid & 63;
    const int lr = lane & 15, quad = lane >> 4;
    const int h = blockIdx.y, b = blockIdx.z;
    const int kvh = h >> 2;
    const unsigned short* kb = qkv + (size_t)(b * S_LEN) * QKV_N + KOFF + kvh * D_K;
    const unsigned short* vb = qkv + (size_t)(b * S_LEN) * QKV_N + VOFF + kvh * D_K;

    const int qtA = blockIdx.x;        // 0..7
    const int qtB = 15 - qtA;          // 8..15
    const int ntA = qtA + 1, ntB = qtB + 1;

    short8 aqA[2], aqB[2];
    {
        const unsigned short* qp = qkv + (size_t)(b * S_LEN + qtA * 64 + w * 16 + lr) * QKV_N
                                   + h * D_K + quad * 8;
        aqA[0] = *(const short8*)qp;
        aqA[1] = *(const short8*)(qp + 32);
        qp = qkv + (size_t)(b * S_LEN + qtB * 64 + w * 16 + lr) * QKV_N + h * D_K + quad * 8;
        aqB[0] = *(const short8*)qp;
        aqB[1] = *(const short8*)(qp + 32);
    }
    f32x4 oaccA[4], oaccB[4];
#pragma unroll
    for (int cf = 0; cf < 4; cf++) {
        oaccA[cf] = (f32x4){0.f, 0.f, 0.f, 0.f};
        oaccB[cf] = (f32x4){0.f, 0.f, 0.f, 0.f};
    }
    float mA[4] = {-1e30f, -1e30f, -1e30f, -1e30f}, lA[4] = {0.f, 0.f, 0.f, 0.f};
    float mB[4] = {-1e30f, -1e30f, -1e30f, -1e30f}, lB[4] = {0.f, 0.f, 0.f, 0.f};

    Pre pre;
    issue_pre(kb, vb, 0, tid, pre);
    for (int t = 0; t < ntB; t++) {
        __syncthreads();                       // prev compute done; LDS free
        commit_pre(Ks, Vt, tid, pre);          // regs -> LDS
        __syncthreads();                       // staging visible
        if (t + 1 < ntB) issue_pre(kb, vb, (t + 1) * 64, tid, pre);  // overlap
        if (t < ntA)
            attn_tile(w, quad, lr, t == qtA, Ks, Vt, Ps, aqA, oaccA, mA, lA);
        attn_tile(w, quad, lr, t == qtB, Ks, Vt, Ps, aqB, oaccB, mB, lB);
    }
#pragma unroll
    for (int r = 0; r < 4; r++) {
        float invA = 1.f / lA[r], invB = 1.f / lB[r];
        int rowA = b * S_LEN + qtA * 64 + w * 16 + quad * 4 + r;
        int rowB = b * S_LEN + qtB * 64 + w * 16 + quad * 4 + r;
#pragma unroll
        for (int cf = 0; cf < 4; cf++) {
            obf[(size_t)rowA * D_MODEL + h * D_K + cf * 16 + lr] = f2bf(oaccA[cf][r] * invA);
            obf[(size_t)rowB * D_MODEL + h * D_K + cf * 16 + lr] = f2bf(oaccB[cf][r] * invB);
        }
    }
}

extern "C" void kernel_launch(void* const* d_in, const int* in_sizes, int n_in,
                              void* d_out, int out_size, void* d_ws, size_t ws_size,
                              hipStream_t stream) {
    const float* x  = (const float*)d_in[0];
    const float* Wq = (const float*)d_in[1];
    const float* bq = (const float*)d_in[2];
    const float* Wk = (const float*)d_in[3];
    const float* bk = (const float*)d_in[4];
    const float* Wv = (const float*)d_in[5];
    const float* bv = (const float*)d_in[6];
    const float* Wo = (const float*)d_in[7];
    const float* bo = (const float*)d_in[8];
    float* out = (float*)d_out;

    // ws (bf16 elems): xbf/obf 8MB | WtQKV 12MB | WtO 8MB | qkv 12MB | bias 12KB = 40MB
    unsigned short* xbf   = (unsigned short*)d_ws;                       // [2048][2048]
    unsigned short* WtQKV = xbf + (size_t)M_ROWS * D_MODEL;              // [3072][2048]
    unsigned short* WtO   = WtQKV + (size_t)QKV_N * D_MODEL;             // [2048][2048]
    unsigned short* qkv   = WtO + (size_t)D_MODEL * D_MODEL;             // [2048][3072]
    float* bias_qkv       = (float*)(qkv + (size_t)M_ROWS * QKV_N);      // [3072]
    unsigned short* obf   = xbf;  // xbf consumed by QKV GEMM before attn writes

    dim3 gb(256);

    cast_bf_kernel<<<(M_ROWS * D_MODEL / 4 + 255) / 256, gb, 0, stream>>>(x, xbf, M_ROWS * D_MODEL / 4);
    wprep_kernel<<<dim3(32, 32, 4), gb, 0, stream>>>(Wq, Wk, Wv, Wo, WtQKV, WtO);
    concat_bias_kernel<<<(QKV_N + 255) / 256, gb, 0, stream>>>(bq, bk, bv, bias_qkv);
    // fused QKV projection (bf16 out): 48 x 16 = 768 blocks
    gemm_bf16_kernel<unsigned short><<<dim3(QKV_N / 64, M_ROWS / 128), gb, 0, stream>>>(
        xbf, WtQKV, bias_qkv, qkv, M_ROWS, QKV_N, D_MODEL);
    // fused RoPE (q scaled by 0.125*log2e for exp2 softmax)
    rope_bf_kernel<<<(M_ROWS * (N_HEAD + N_KV_HEAD) * 32 + 255) / 256, gb, 0, stream>>>(qkv);
    // attention: paired q-tiles + register prefetch, 512 blocks
    attn_mfma_kernel<<<dim3(8, N_HEAD, B_SZ), gb, 0, stream>>>(qkv, obf);
    // O projection (fp32 out): 32 x 16 = 512 blocks
    gemm_bf16_kernel<float><<<dim3(D_MODEL / 64, M_ROWS / 128), gb, 0, stream>>>(
        obf, WtO, bo, out, M_ROWS, D_MODEL, D_MODEL);
}